// Round 17
// baseline (1156.497 us; speedup 1.0000x reference)
//
#include <hip/hip_runtime.h>
#include <hip/hip_cooperative_groups.h>
#include <math.h>

namespace cg = cooperative_groups;

#define PS 6
#define P2 36
#define CI 32
#define OO 32
#define KC 288
#define KCO 9216
#define EPSF 1e-9f
#define LOG2PI_F 1.8378770664093455f

/* workspace float offsets */
#define ZZ_OFF   0u            /* 2,654,208 floats */
#define RR_OFF   2654208u      /* 2,654,208 floats */
#define WT_OFF   5308416u      /* 147,456 floats */
#define PART_OFF 5455872u      /* 1,216,512 floats */

__device__ __forceinline__ int covr(int x){
  int cnt = 0;
#pragma unroll
  for (int r = 0; r < 6; ++r) { int i = x - 2*r; cnt += (i >= 0 && i <= 2) ? 1 : 0; }
  return cnt;
}

/* ================= cooperative single-launch (grid 576, 2 units/block) ================= */
__global__ __launch_bounds__(256, 3) void em_coop(
    const float* __restrict__ inp, const float* __restrict__ w,
    const float* __restrict__ beta_v, const float* __restrict__ beta_a,
    float* __restrict__ ws, float* __restrict__ out)
{
  cg::grid_group grid = cg::this_grid();

  float* zzg  = ws + ZZ_OFF;
  float* rrg  = ws + RR_OFF;
  float* wT   = ws + WT_OFF;
  float* part = ws + PART_OFF;

  __shared__ float s_pose[2][1152];
  __shared__ float s_ra[2][72];
  __shared__ float s_red[4224];
  __shared__ float s_mean[512];
  __shared__ float s_i2v[512];
  __shared__ float s_cost[32];
  __shared__ float s_lvs[32];
  __shared__ float s_lc[32];

  const int b = blockIdx.x;          /* 0..575 */
  const int t = threadIdx.x;
  const int np = b % 288;            /* block's parent id; units k4 = k4a, k4a+2 */
  const int k4a = b / 288;           /* 0 or 1 */
  const int n = np / P2, p = np % P2;
  const int pr = p / PS, pc = p % PS;

  /* phase 0: wtrans (576*256 = 147456 exact) + pose staging for both units */
  {
    int e = b * 256 + t;
    int bb = e & 3, o = (e >> 2) & 31, c = (e >> 7) & 3, k = e >> 9;
    wT[e] = w[k*512 + o*16 + bb*4 + c];
  }
  const float* ibase = inp + (size_t)n * (196*32*17);
#pragma unroll
  for (int u = 0; u < 2; ++u) {
    const int k0 = (k4a + 2*u) * 72;
    for (int e = t; e < 288; e += 256) {    /* 72 rows * 4 float4 */
      int kl = e >> 2, v4 = e & 3;
      int k = k0 + kl;
      int kk = k >> 5, ci = k & 31;
      const float* src = ibase + (size_t)(((pr*2 + kk/3)*14 + (pc*2 + kk%3))*32 + ci)*17 + v4*4;
      ((float4*)s_pose[u])[e] = *(const float4*)src;
    }
    if (t < 72) {
      int k = k0 + t; int kk = k >> 5, ci = k & 31;
      int x = pr*2 + kk/3, y = pc*2 + kk%3;
      float a = ibase[((x*14 + y)*32 + ci)*17 + 16];
      s_ra[u][t] = a / (float)(covr(x) * covr(y) * OO);
    }
  }
  __threadfence();
  grid.sync();

  for (int it = 0; it < 3; ++it) {
    /* ---- phase A: moments, both units sequentially ---- */
    for (int u = 0; u < 2; ++u) {
      const int k4 = k4a + 2*u;
      const int k0 = k4 * 72;
      const int q = t >> 5, o = t & 31;
      float srr = 0.f;
      float m1[16], m2[16];
#pragma unroll
      for (int j = 0; j < 16; ++j) { m1[j] = 0.f; m2[j] = 0.f; }

      const float* rp = rrg + (size_t)np * KCO;
#pragma unroll 3
      for (int ks = 0; ks < 9; ++ks) {
        int kl = q*9 + ks;
        int k  = k0 + kl;
        float rra = (it == 0) ? s_ra[u][kl] : rp[(k << 5) + o];
        const float4* pk  = (const float4*)s_pose[u] + (kl << 2);
        const float4* wkb = (const float4*)wT + ((size_t)k << 7) + o;
        float4 w0 = wkb[0], w1 = wkb[32], w2 = wkb[64], w3 = wkb[96];
        srr += rra;
#pragma unroll
        for (int a = 0; a < 4; ++a) {
          float4 A = pk[a];
          float v0 = A.x*w0.x + A.y*w0.y + A.z*w0.z + A.w*w0.w;
          float v1 = A.x*w1.x + A.y*w1.y + A.z*w1.z + A.w*w1.w;
          float v2 = A.x*w2.x + A.y*w2.y + A.z*w2.z + A.w*w2.w;
          float v3 = A.x*w3.x + A.y*w3.y + A.z*w3.z + A.w*w3.w;
          float r0 = rra*v0, r1 = rra*v1, r2 = rra*v2, r3 = rra*v3;
          m1[a*4+0] += r0;    m1[a*4+1] += r1;    m1[a*4+2] += r2;    m1[a*4+3] += r3;
          m2[a*4+0] += r0*v0; m2[a*4+1] += r1*v1; m2[a*4+2] += r2*v2; m2[a*4+3] += r3*v3;
        }
      }
      srr += __shfl_xor(srr, 32, 64);
#pragma unroll
      for (int j = 0; j < 16; ++j) {
        m1[j] += __shfl_xor(m1[j], 32, 64);
        m2[j] += __shfl_xor(m2[j], 32, 64);
      }
      {
        const int lane = t & 63, wv = t >> 6;
        if (lane < 32) {
          float* rb = s_red + wv*1056 + lane*33;
          rb[0] = srr;
#pragma unroll
          for (int j = 0; j < 16; ++j) { rb[1+j] = m1[j]; rb[17+j] = m2[j]; }
        }
      }
      __syncthreads();
      float* pb = part + (size_t)(np*4 + k4) * 1056;
      for (int u2 = t; u2 < 1056; u2 += 256) {
        pb[u2] = s_red[u2] + s_red[1056+u2] + s_red[2112+u2] + s_red[3168+u2];
      }
      __syncthreads();
    }
    __threadfence();
    grid.sync();

    if (it == 2) break;

    /* ---- phase B: stats (redundant per np-pair) + zz for both units ---- */
    for (int tt = t; tt < 512; tt += 256) {
      const int so = tt >> 4, h = tt & 15;
      const float* pb = part + (size_t)np * 4224 + so*33;
      float rs = pb[0]    + pb[1056]      + pb[2112]      + pb[3168];
      float a1 = pb[1+h]  + pb[1056+1+h]  + pb[2112+1+h]  + pb[3168+1+h];
      float a2 = pb[17+h] + pb[1056+17+h] + pb[2112+17+h] + pb[3168+17+h];
      float S    = rs + EPSF;
      float mean = a1 / S;
      float var  = fmaxf(a2 / S - mean*mean, 0.f) + EPSF;
      float lvh  = __logf(var);
      float ch   = (beta_v[so] + 0.5f * lvh) * rs;
      float lv   = lvh;
#pragma unroll
      for (int d = 1; d < 16; d <<= 1) {
        ch += __shfl_xor(ch, d, 64);
        lv += __shfl_xor(lv, d, 64);
      }
      s_mean[tt] = mean;
      s_i2v[tt]  = 0.5f / var;
      if (h == 0) { s_cost[so] = ch; s_lvs[so] = lv; }
    }
    __syncthreads();
    if (t < OO) {
      float cm = 0.f;
#pragma unroll
      for (int oi = 0; oi < OO; ++oi) cm += s_cost[oi];
      cm *= (1.f / OO);
      float ssq = 0.f;
#pragma unroll
      for (int oi = 0; oi < OO; ++oi) { float d = s_cost[oi] - cm; ssq += d*d; }
      float sd = sqrtf(ssq * (1.f / OO));
      const float INVT = (it == 0) ? 5.0e-4f : 9.75e-4f;
      float arg = INVT * (beta_a[t] + (cm - s_cost[t]) / (sd + EPSF));
      float aj  = 1.f / (1.f + __expf(-arg));
      s_lc[t] = __logf(aj + EPSF) - 0.5f * (s_lvs[t] + 16.f * LOG2PI_F);
    }
    __syncthreads();
    {
      const int oz = t & 31;
      const float lc = s_lc[oz];
      const float4* mo4 = (const float4*)(s_mean + (oz << 4));
      const float4* io4 = (const float4*)(s_i2v  + (oz << 4));
      float4 M0 = mo4[0], M1 = mo4[1], M2 = mo4[2], M3 = mo4[3];
      float4 I0 = io4[0], I1 = io4[1], I2 = io4[2], I3 = io4[3];
      for (int u = 0; u < 2; ++u) {
        const int k0 = (k4a + 2*u) * 72;
        float* zb = zzg + (size_t)np * KCO + ((size_t)k0 << 5);
        for (int r = t; r < 2304; r += 256) {
          int kl = r >> 5;
          int k  = k0 + kl;
          const float4* pk  = (const float4*)s_pose[u] + (kl << 2);
          const float4* wkb = (const float4*)wT + ((size_t)k << 7) + oz;
          float4 w0 = wkb[0], w1 = wkb[32], w2 = wkb[64], w3 = wkb[96];
          float ssum = 0.f;
          float4 A;
          A = pk[0];
          {
            float x0 = A.x*w0.x + A.y*w0.y + A.z*w0.z + A.w*w0.w;
            float x1 = A.x*w1.x + A.y*w1.y + A.z*w1.z + A.w*w1.w;
            float x2 = A.x*w2.x + A.y*w2.y + A.z*w2.z + A.w*w2.w;
            float x3 = A.x*w3.x + A.y*w3.y + A.z*w3.z + A.w*w3.w;
            float d0 = x0-M0.x, d1 = x1-M0.y, d2 = x2-M0.z, d3 = x3-M0.w;
            ssum += d0*d0*I0.x + d1*d1*I0.y + d2*d2*I0.z + d3*d3*I0.w;
          }
          A = pk[1];
          {
            float x0 = A.x*w0.x + A.y*w0.y + A.z*w0.z + A.w*w0.w;
            float x1 = A.x*w1.x + A.y*w1.y + A.z*w1.z + A.w*w1.w;
            float x2 = A.x*w2.x + A.y*w2.y + A.z*w2.z + A.w*w2.w;
            float x3 = A.x*w3.x + A.y*w3.y + A.z*w3.z + A.w*w3.w;
            float d0 = x0-M1.x, d1 = x1-M1.y, d2 = x2-M1.z, d3 = x3-M1.w;
            ssum += d0*d0*I1.x + d1*d1*I1.y + d2*d2*I1.z + d3*d3*I1.w;
          }
          A = pk[2];
          {
            float x0 = A.x*w0.x + A.y*w0.y + A.z*w0.z + A.w*w0.w;
            float x1 = A.x*w1.x + A.y*w1.y + A.z*w1.z + A.w*w1.w;
            float x2 = A.x*w2.x + A.y*w2.y + A.z*w2.z + A.w*w2.w;
            float x3 = A.x*w3.x + A.y*w3.y + A.z*w3.z + A.w*w3.w;
            float d0 = x0-M2.x, d1 = x1-M2.y, d2 = x2-M2.z, d3 = x3-M2.w;
            ssum += d0*d0*I2.x + d1*d1*I2.y + d2*d2*I2.z + d3*d3*I2.w;
          }
          A = pk[3];
          {
            float x0 = A.x*w0.x + A.y*w0.y + A.z*w0.z + A.w*w0.w;
            float x1 = A.x*w1.x + A.y*w1.y + A.z*w1.z + A.w*w1.w;
            float x2 = A.x*w2.x + A.y*w2.y + A.z*w2.z + A.w*w2.w;
            float x3 = A.x*w3.x + A.y*w3.y + A.z*w3.z + A.w*w3.w;
            float d0 = x0-M3.x, d1 = x1-M3.y, d2 = x2-M3.z, d3 = x3-M3.w;
            ssum += d0*d0*I3.x + d1*d1*I3.y + d2*d2*I3.z + d3*d3*I3.w;
          }
          zb[r] = lc - ssum;
        }
      }
    }
    __threadfence();
    grid.sync();

    /* ---- phase C: childnorm, 2 chunks per block ---- */
    for (int u = 0; u < 2; ++u) {
      const int tg = (b + u*576) * 256 + t;
      if (tg < 173056) {
        const int g = tg >> 2, slot = tg & 3;
        const int cn_n  = g / (169*32);
        const int rem   = g % (169*32);
        const int sc    = rem >> 5, cn_ci = rem & 31;
        const int cx = sc / 13, cy = sc % 13;

        int base = -1; int cnt = 0;
#pragma unroll
        for (int r = 0; r < 6; ++r) {
          int i = cx - 2*r;
          if (i < 0 || i > 2) continue;
#pragma unroll
          for (int c2 = 0; c2 < 6; ++c2) {
            int j = cy - 2*c2;
            if (j < 0 || j > 2) continue;
            if (cnt == slot) base = (((cn_n*P2 + r*6+c2)*9 + i*3+j)*CI + cn_ci) << 5;
            ++cnt;
          }
        }
        const float4* z4 = (base >= 0) ? (const float4*)(zzg + base) : (const float4*)zzg;
        float4 zv[8];
#pragma unroll
        for (int q2 = 0; q2 < 8; ++q2) zv[q2] = z4[q2];

        float m = -1e30f;
        if (base >= 0) {
#pragma unroll
          for (int q2 = 0; q2 < 8; ++q2) {
            float4 v = zv[q2];
            m = fmaxf(m, fmaxf(fmaxf(v.x, v.y), fmaxf(v.z, v.w)));
          }
        }
        m = fmaxf(m, __shfl_xor(m, 1, 64));
        m = fmaxf(m, __shfl_xor(m, 2, 64));

        float den = 0.f;
        float e[32];
        if (base >= 0) {
#pragma unroll
          for (int q2 = 0; q2 < 8; ++q2) {
            float4 v = zv[q2];
            e[q2*4+0] = __expf(v.x - m); e[q2*4+1] = __expf(v.y - m);
            e[q2*4+2] = __expf(v.z - m); e[q2*4+3] = __expf(v.w - m);
            den += e[q2*4+0] + e[q2*4+1] + e[q2*4+2] + e[q2*4+3];
          }
        }
        den += __shfl_xor(den, 1, 64);
        den += __shfl_xor(den, 2, 64);

        const float act = inp[(((size_t)cn_n*196 + cx*14 + cy)*32 + cn_ci)*17 + 16];
        float s = act / (den + EPSF);

        if (base >= 0) {
          float4* r4 = (float4*)(rrg + base);
#pragma unroll
          for (int q2 = 0; q2 < 8; ++q2) {
            float4 rv;
            rv.x = e[q2*4+0]*s; rv.y = e[q2*4+1]*s; rv.z = e[q2*4+2]*s; rv.w = e[q2*4+3]*s;
            r4[q2] = rv;
          }
        }
      }
    }
    __threadfence();
    grid.sync();
  }

  /* ---- final statsout: blocks 0..287 ---- */
  if (b < 288) {
    for (int tt = t; tt < 512; tt += 256) {
      const int so = tt >> 4, h = tt & 15;
      const float* pb = part + (size_t)b * 4224 + so*33;
      float rs = pb[0]    + pb[1056]      + pb[2112]      + pb[3168];
      float a1 = pb[1+h]  + pb[1056+1+h]  + pb[2112+1+h]  + pb[3168+1+h];
      float a2 = pb[17+h] + pb[1056+17+h] + pb[2112+17+h] + pb[3168+17+h];
      float S = rs + EPSF;
      float mean = a1 / S;
      float var  = fmaxf(a2 / S - mean*mean, 0.f) + EPSF;
      float ch   = (beta_v[so] + 0.5f * __logf(var)) * rs;
#pragma unroll
      for (int d = 1; d < 16; d <<= 1) ch += __shfl_xor(ch, d, 64);
      out[((size_t)b*OO + so)*17 + 1 + h] = mean;
      if (h == 0) s_cost[so] = ch;
    }
    __syncthreads();
    if (t < OO) {
      float cm = 0.f;
#pragma unroll
      for (int oi = 0; oi < OO; ++oi) cm += s_cost[oi];
      cm *= (1.f / OO);
      float ssq = 0.f;
#pragma unroll
      for (int oi = 0; oi < OO; ++oi) { float d = s_cost[oi] - cm; ssq += d*d; }
      float sd = sqrtf(ssq * (1.f / OO));
      float arg = 1.42625e-3f * (beta_a[t] + (cm - s_cost[t]) / (sd + EPSF));
      float aj  = 1.f / (1.f + __expf(-arg));
      out[((size_t)b*OO + t)*17] = aj;
    }
  }
}

/* ================= fallback multi-kernel path (R16 champion) ================= */
__global__ __launch_bounds__(256) void wtrans_kernel(const float* __restrict__ w,
                                                     float* __restrict__ wT)
{
  int e = blockIdx.x * 256 + threadIdx.x;
  int b = e & 3, o = (e >> 2) & 31, c = (e >> 7) & 3, k = e >> 9;
  wT[e] = w[k*512 + o*16 + b*4 + c];
}

template<bool FIRST>
__global__ __launch_bounds__(256, 5) void moments_kernel(
    const float* __restrict__ inp, const float* __restrict__ wT,
    const float* __restrict__ rrg, float* __restrict__ part)
{
  __shared__ float s_pose[72*16];
  __shared__ float s_ra[72];
  __shared__ float s_red[4*1056];

  const int blk = blockIdx.x;
  const int np = blk % 288, k4 = blk / 288;
  const int n = np / P2, p = np % P2;
  const int pr = p / PS, pc = p % PS;
  const int t = threadIdx.x;
  const int k0 = k4 * 72;

  const float* ibase = inp + (size_t)n * (196*32*17);
  for (int e = t; e < 72*4; e += 256) {
    int kl = e >> 2, v4 = e & 3;
    int k = k0 + kl;
    int kk = k >> 5, ci = k & 31;
    const float* src = ibase + (size_t)(((pr*2 + kk/3)*14 + (pc*2 + kk%3))*32 + ci)*17 + v4*4;
    ((float4*)s_pose)[e] = *(const float4*)src;
  }
  if (FIRST && t < 72) {
    int k = k0 + t; int kk = k >> 5, ci = k & 31;
    int x = pr*2 + kk/3, y = pc*2 + kk%3;
    float a = ibase[((x*14 + y)*32 + ci)*17 + 16];
    s_ra[t] = a / (float)(covr(x) * covr(y) * OO);
  }
  __syncthreads();

  const int q = t >> 5, o = t & 31;
  float srr = 0.f;
  float m1[16], m2[16];
#pragma unroll
  for (int j = 0; j < 16; ++j) { m1[j] = 0.f; m2[j] = 0.f; }

  const float* rp = rrg + (size_t)np * KCO;
#pragma unroll 3
  for (int ks = 0; ks < 9; ++ks) {
    int kl = q*9 + ks;
    int k  = k0 + kl;
    float rra = FIRST ? s_ra[kl] : rp[(k << 5) + o];
    const float4* pk  = (const float4*)s_pose + (kl << 2);
    const float4* wkb = (const float4*)wT + ((size_t)k << 7) + o;
    float4 w0 = wkb[0], w1 = wkb[32], w2 = wkb[64], w3 = wkb[96];
    srr += rra;
#pragma unroll
    for (int a = 0; a < 4; ++a) {
      float4 A = pk[a];
      float v0 = A.x*w0.x + A.y*w0.y + A.z*w0.z + A.w*w0.w;
      float v1 = A.x*w1.x + A.y*w1.y + A.z*w1.z + A.w*w1.w;
      float v2 = A.x*w2.x + A.y*w2.y + A.z*w2.z + A.w*w2.w;
      float v3 = A.x*w3.x + A.y*w3.y + A.z*w3.z + A.w*w3.w;
      float r0 = rra*v0, r1 = rra*v1, r2 = rra*v2, r3 = rra*v3;
      m1[a*4+0] += r0;    m1[a*4+1] += r1;    m1[a*4+2] += r2;    m1[a*4+3] += r3;
      m2[a*4+0] += r0*v0; m2[a*4+1] += r1*v1; m2[a*4+2] += r2*v2; m2[a*4+3] += r3*v3;
    }
  }

  srr += __shfl_xor(srr, 32, 64);
#pragma unroll
  for (int j = 0; j < 16; ++j) {
    m1[j] += __shfl_xor(m1[j], 32, 64);
    m2[j] += __shfl_xor(m2[j], 32, 64);
  }
  {
    const int lane = t & 63, wv = t >> 6;
    if (lane < 32) {
      float* rb = s_red + wv*1056 + lane*33;
      rb[0] = srr;
#pragma unroll
      for (int j = 0; j < 16; ++j) { rb[1+j] = m1[j]; rb[17+j] = m2[j]; }
    }
  }
  __syncthreads();
  float* pb = part + (size_t)(np*4 + k4) * 1056;
  for (int u = t; u < 1056; u += 256) {
    float s = s_red[u] + s_red[1056+u] + s_red[2112+u] + s_red[3168+u];
    pb[u] = s;
  }
}

template<int IT>
__global__ __launch_bounds__(512, 4) void zzstats_kernel(
    const float* __restrict__ inp, const float* __restrict__ wT,
    const float* __restrict__ part,
    const float* __restrict__ beta_v, const float* __restrict__ beta_a,
    float* __restrict__ zzg)
{
  __shared__ float s_pose[72*16];
  __shared__ float s_mean[512];
  __shared__ float s_i2v[512];
  __shared__ float s_cost[OO];
  __shared__ float s_lvs[OO];
  __shared__ float s_lc[OO];

  const int blk = blockIdx.x;
  const int np = blk % 288, k4 = blk / 288;
  const int n = np / P2, p = np % P2;
  const int pr = p / PS, pc = p % PS;
  const int t = threadIdx.x;
  const int k0 = k4 * 72;

  const float* ibase = inp + (size_t)n * (196*32*17);
  for (int e = t; e < 72*4; e += 512) {
    int kl = e >> 2, v4 = e & 3;
    int k = k0 + kl;
    int kk = k >> 5, ci = k & 31;
    const float* src = ibase + (size_t)(((pr*2 + kk/3)*14 + (pc*2 + kk%3))*32 + ci)*17 + v4*4;
    ((float4*)s_pose)[e] = *(const float4*)src;
  }

  {
    const int so = t >> 4, h = t & 15;
    const float* pb = part + (size_t)np * 4224 + so*33;
    float rs = pb[0]        + pb[1056]        + pb[2112]        + pb[3168];
    float a1 = pb[1+h]      + pb[1056+1+h]    + pb[2112+1+h]    + pb[3168+1+h];
    float a2 = pb[17+h]     + pb[1056+17+h]   + pb[2112+17+h]   + pb[3168+17+h];
    float S    = rs + EPSF;
    float mean = a1 / S;
    float var  = fmaxf(a2 / S - mean*mean, 0.f) + EPSF;
    float lvh  = __logf(var);
    float ch   = (beta_v[so] + 0.5f * lvh) * rs;
    float lv   = lvh;
#pragma unroll
    for (int d = 1; d < 16; d <<= 1) {
      ch += __shfl_xor(ch, d, 64);
      lv += __shfl_xor(lv, d, 64);
    }
    s_mean[t] = mean;
    s_i2v[t]  = 0.5f / var;
    if (h == 0) { s_cost[so] = ch; s_lvs[so] = lv; }
  }
  __syncthreads();

  if (t < OO) {
    float cm = 0.f;
#pragma unroll
    for (int oi = 0; oi < OO; ++oi) cm += s_cost[oi];
    cm *= (1.f / OO);
    float ssq = 0.f;
#pragma unroll
    for (int oi = 0; oi < OO; ++oi) { float d = s_cost[oi] - cm; ssq += d*d; }
    float sd = sqrtf(ssq * (1.f / OO));
    const float INVT = (IT==0) ? 5.0e-4f : 9.75e-4f;
    float arg = INVT * (beta_a[t] + (cm - s_cost[t]) / (sd + EPSF));
    float aj  = 1.f / (1.f + __expf(-arg));
    s_lc[t] = __logf(aj + EPSF) - 0.5f * (s_lvs[t] + 16.f * LOG2PI_F);
  }
  __syncthreads();

  {
    const int oz = t & 31;
    const float lc = s_lc[oz];
    const float4* mo4 = (const float4*)(s_mean + (oz << 4));
    const float4* io4 = (const float4*)(s_i2v  + (oz << 4));
    float4 M0 = mo4[0], M1 = mo4[1], M2 = mo4[2], M3 = mo4[3];
    float4 I0 = io4[0], I1 = io4[1], I2 = io4[2], I3 = io4[3];
    float* zb = zzg + (size_t)np * KCO + ((size_t)k0 << 5);
    for (int r = t; r < 2304; r += 512) {
      int kl = r >> 5;
      int k  = k0 + kl;
      const float4* pk  = (const float4*)s_pose + (kl << 2);
      const float4* wkb = (const float4*)wT + ((size_t)k << 7) + oz;
      float4 w0 = wkb[0], w1 = wkb[32], w2 = wkb[64], w3 = wkb[96];
      float ssum = 0.f;
      float4 A;
      A = pk[0];
      {
        float x0 = A.x*w0.x + A.y*w0.y + A.z*w0.z + A.w*w0.w;
        float x1 = A.x*w1.x + A.y*w1.y + A.z*w1.z + A.w*w1.w;
        float x2 = A.x*w2.x + A.y*w2.y + A.z*w2.z + A.w*w2.w;
        float x3 = A.x*w3.x + A.y*w3.y + A.z*w3.z + A.w*w3.w;
        float d0 = x0-M0.x, d1 = x1-M0.y, d2 = x2-M0.z, d3 = x3-M0.w;
        ssum += d0*d0*I0.x + d1*d1*I0.y + d2*d2*I0.z + d3*d3*I0.w;
      }
      A = pk[1];
      {
        float x0 = A.x*w0.x + A.y*w0.y + A.z*w0.z + A.w*w0.w;
        float x1 = A.x*w1.x + A.y*w1.y + A.z*w1.z + A.w*w1.w;
        float x2 = A.x*w2.x + A.y*w2.y + A.z*w2.z + A.w*w2.w;
        float x3 = A.x*w3.x + A.y*w3.y + A.z*w3.z + A.w*w3.w;
        float d0 = x0-M1.x, d1 = x1-M1.y, d2 = x2-M1.z, d3 = x3-M1.w;
        ssum += d0*d0*I1.x + d1*d1*I1.y + d2*d2*I1.z + d3*d3*I1.w;
      }
      A = pk[2];
      {
        float x0 = A.x*w0.x + A.y*w0.y + A.z*w0.z + A.w*w0.w;
        float x1 = A.x*w1.x + A.y*w1.y + A.z*w1.z + A.w*w1.w;
        float x2 = A.x*w2.x + A.y*w2.y + A.z*w2.z + A.w*w2.w;
        float x3 = A.x*w3.x + A.y*w3.y + A.z*w3.z + A.w*w3.w;
        float d0 = x0-M2.x, d1 = x1-M2.y, d2 = x2-M2.z, d3 = x3-M2.w;
        ssum += d0*d0*I2.x + d1*d1*I2.y + d2*d2*I2.z + d3*d3*I2.w;
      }
      A = pk[3];
      {
        float x0 = A.x*w0.x + A.y*w0.y + A.z*w0.z + A.w*w0.w;
        float x1 = A.x*w1.x + A.y*w1.y + A.z*w1.z + A.w*w1.w;
        float x2 = A.x*w2.x + A.y*w2.y + A.z*w2.z + A.w*w2.w;
        float x3 = A.x*w3.x + A.y*w3.y + A.z*w3.z + A.w*w3.w;
        float d0 = x0-M3.x, d1 = x1-M3.y, d2 = x2-M3.z, d3 = x3-M3.w;
        ssum += d0*d0*I3.x + d1*d1*I3.y + d2*d2*I3.z + d3*d3*I3.w;
      }
      zb[r] = lc - ssum;
    }
  }
}

__global__ __launch_bounds__(512) void statsout_kernel(
    const float* __restrict__ part,
    const float* __restrict__ beta_v, const float* __restrict__ beta_a,
    float* __restrict__ out)
{
  __shared__ float s_cost[OO];
  const int np = blockIdx.x;
  const int t = threadIdx.x;
  const int o = t >> 4, h = t & 15;

  const float* pb = part + (size_t)np * 4224 + o*33;
  float rs = pb[0]    + pb[1056]      + pb[2112]      + pb[3168];
  float a1 = pb[1+h]  + pb[1056+1+h]  + pb[2112+1+h]  + pb[3168+1+h];
  float a2 = pb[17+h] + pb[1056+17+h] + pb[2112+17+h] + pb[3168+17+h];
  float S = rs + EPSF;
  float mean = a1 / S;
  float var  = fmaxf(a2 / S - mean*mean, 0.f) + EPSF;
  float ch   = (beta_v[o] + 0.5f * __logf(var)) * rs;
#pragma unroll
  for (int d = 1; d < 16; d <<= 1) ch += __shfl_xor(ch, d, 64);
  if (h == 0) s_cost[o] = ch;
  __syncthreads();

  float cm = 0.f;
#pragma unroll
  for (int oi = 0; oi < OO; ++oi) cm += s_cost[oi];
  cm *= (1.f / OO);
  float ssq = 0.f;
#pragma unroll
  for (int oi = 0; oi < OO; ++oi) { float d = s_cost[oi] - cm; ssq += d*d; }
  float sd = sqrtf(ssq * (1.f / OO));
  float arg = 1.42625e-3f * (beta_a[o] + (cm - s_cost[o]) / (sd + EPSF));
  float aj  = 1.f / (1.f + __expf(-arg));

  out[((size_t)np*OO + o)*17 + 1 + h] = mean;
  if (h == 0) out[((size_t)np*OO + o)*17] = aj;
}

__global__ __launch_bounds__(256) void childnorm_kernel(
    const float* __restrict__ inp, const float* __restrict__ zzg,
    float* __restrict__ rrg)
{
  const int tg = blockIdx.x * 256 + threadIdx.x;
  const int g = tg >> 2, slot = tg & 3;
  const int n   = g / (169*32);
  const int rem = g % (169*32);
  const int sc  = rem >> 5, ci = rem & 31;
  const int x = sc / 13, y = sc % 13;

  int base = -1; int cnt = 0;
#pragma unroll
  for (int r = 0; r < 6; ++r) {
    int i = x - 2*r;
    if (i < 0 || i > 2) continue;
#pragma unroll
    for (int c2 = 0; c2 < 6; ++c2) {
      int j = y - 2*c2;
      if (j < 0 || j > 2) continue;
      if (cnt == slot) base = (((n*P2 + r*6+c2)*9 + i*3+j)*CI + ci) << 5;
      ++cnt;
    }
  }

  const float4* z4 = (base >= 0) ? (const float4*)(zzg + base) : (const float4*)zzg;
  float4 zv[8];
#pragma unroll
  for (int q = 0; q < 8; ++q) zv[q] = z4[q];

  float m = -1e30f;
  if (base >= 0) {
#pragma unroll
    for (int q = 0; q < 8; ++q) {
      float4 v = zv[q];
      m = fmaxf(m, fmaxf(fmaxf(v.x, v.y), fmaxf(v.z, v.w)));
    }
  }
  m = fmaxf(m, __shfl_xor(m, 1, 64));
  m = fmaxf(m, __shfl_xor(m, 2, 64));

  float den = 0.f;
  float e[32];
  if (base >= 0) {
#pragma unroll
    for (int q = 0; q < 8; ++q) {
      float4 v = zv[q];
      e[q*4+0] = __expf(v.x - m); e[q*4+1] = __expf(v.y - m);
      e[q*4+2] = __expf(v.z - m); e[q*4+3] = __expf(v.w - m);
      den += e[q*4+0] + e[q*4+1] + e[q*4+2] + e[q*4+3];
    }
  }
  den += __shfl_xor(den, 1, 64);
  den += __shfl_xor(den, 2, 64);

  const float act = inp[(((size_t)n*196 + x*14 + y)*32 + ci)*17 + 16];
  float s = act / (den + EPSF);

  if (base >= 0) {
    float4* r4 = (float4*)(rrg + base);
#pragma unroll
    for (int q = 0; q < 8; ++q) {
      float4 rv;
      rv.x = e[q*4+0]*s; rv.y = e[q*4+1]*s; rv.z = e[q*4+2]*s; rv.w = e[q*4+3]*s;
      r4[q] = rv;
    }
  }
}

extern "C" void kernel_launch(void* const* d_in, const int* in_sizes, int n_in,
                              void* d_out, int out_size, void* d_ws, size_t ws_size,
                              hipStream_t stream)
{
  (void)in_sizes; (void)n_in; (void)out_size; (void)ws_size;
  const float* inp = (const float*)d_in[0];
  const float* w   = (const float*)d_in[1];
  const float* bv  = (const float*)d_in[2];
  const float* ba  = (const float*)d_in[3];
  float* out = (float*)d_out;
  float* ws  = (float*)d_ws;

  void* args[6] = { (void*)&inp, (void*)&w, (void*)&bv, (void*)&ba, (void*)&ws, (void*)&out };
  hipError_t err = hipLaunchCooperativeKernel((const void*)em_coop,
                                              dim3(576), dim3(256), args, 0, stream);
  if (err == hipSuccess) return;

  /* fallback: R16 champion path */
  float* zz   = ws + ZZ_OFF;
  float* rr   = ws + RR_OFF;
  float* wT   = ws + WT_OFF;
  float* part = ws + PART_OFF;

  wtrans_kernel<<<576, 256, 0, stream>>>(w, wT);

  moments_kernel<true ><<<1152, 256, 0, stream>>>(inp, wT, rr, part);
  zzstats_kernel<0><<<1152, 512, 0, stream>>>(inp, wT, part, bv, ba, zz);
  childnorm_kernel<<<676, 256, 0, stream>>>(inp, zz, rr);

  moments_kernel<false><<<1152, 256, 0, stream>>>(inp, wT, rr, part);
  zzstats_kernel<1><<<1152, 512, 0, stream>>>(inp, wT, part, bv, ba, zz);
  childnorm_kernel<<<676, 256, 0, stream>>>(inp, zz, rr);

  moments_kernel<false><<<1152, 256, 0, stream>>>(inp, wT, rr, part);
  statsout_kernel<<<288, 512, 0, stream>>>(part, bv, ba, out);
}

// Round 18
// 107.884 us; speedup vs baseline: 10.7198x; 10.7198x over previous
//
#include <hip/hip_runtime.h>
#include <math.h>

#define PS 6
#define P2 36
#define CI 32
#define OO 32
#define KC 288
#define KCO 9216
#define EPSF 1e-9f
#define LOG2PI_F 1.8378770664093455f

/* workspace float offsets */
#define ZZ_OFF   0u            /* 2,654,208 floats */
#define RR_OFF   2654208u      /* 2,654,208 floats */
#define WT_OFF   5308416u      /* 147,456 floats */
#define PART_OFF 5455872u      /* 1152*1056 = 1,216,512 floats */

__device__ __forceinline__ int covr(int x){
  int cnt = 0;
#pragma unroll
  for (int r = 0; r < 6; ++r) { int i = x - 2*r; cnt += (i >= 0 && i <= 2) ? 1 : 0; }
  return cnt;
}

/* wT[((k*4+c)*32+o)*4+b] = w[k][o][b][c] */
__global__ __launch_bounds__(256) void wtrans_kernel(const float* __restrict__ w,
                                                     float* __restrict__ wT)
{
  int e = blockIdx.x * 256 + threadIdx.x;   /* 147456 */
  int b = e & 3, o = (e >> 2) & 31, c = (e >> 7) & 3, k = e >> 9;
  wT[e] = w[k*512 + o*16 + b*4 + c];
}

/* ---- K1: partial moments. grid = 1152, k4-MAJOR: np = blk%288, k4 = blk/288.
   block 256 = (q,o); 9 vote-rows per thread; float4 pose staging. ---- */
template<bool FIRST>
__global__ __launch_bounds__(256, 5) void moments_kernel(
    const float* __restrict__ inp, const float* __restrict__ wT,
    const float* __restrict__ rrg, float* __restrict__ part)
{
  __shared__ float s_pose[72*16];
  __shared__ float s_ra[72];
  __shared__ float s_red[4*1056];

  const int blk = blockIdx.x;
  const int np = blk % 288, k4 = blk / 288;     /* k4-major for wT L1 reuse */
  const int n = np / P2, p = np % P2;
  const int pr = p / PS, pc = p % PS;
  const int t = threadIdx.x;
  const int k0 = k4 * 72;

  const float* ibase = inp + (size_t)n * (196*32*17);
  /* pose staging: 72 rows * 4 float4s (16 contiguous floats per row, 4B-aligned) */
  for (int e = t; e < 72*4; e += 256) {
    int kl = e >> 2, v4 = e & 3;
    int k = k0 + kl;
    int kk = k >> 5, ci = k & 31;
    const float* src = ibase + (size_t)(((pr*2 + kk/3)*14 + (pc*2 + kk%3))*32 + ci)*17 + v4*4;
    ((float4*)s_pose)[e] = *(const float4*)src;
  }
  if (FIRST && t < 72) {
    int k = k0 + t; int kk = k >> 5, ci = k & 31;
    int x = pr*2 + kk/3, y = pc*2 + kk%3;
    float a = ibase[((x*14 + y)*32 + ci)*17 + 16];
    s_ra[t] = a / (float)(covr(x) * covr(y) * OO);
  }
  __syncthreads();

  const int q = t >> 5, o = t & 31;
  float srr = 0.f;
  float m1[16], m2[16];
#pragma unroll
  for (int j = 0; j < 16; ++j) { m1[j] = 0.f; m2[j] = 0.f; }

  const float* rp = rrg + (size_t)np * KCO;
#pragma unroll 3
  for (int ks = 0; ks < 9; ++ks) {
    int kl = q*9 + ks;
    int k  = k0 + kl;
    float rra = FIRST ? s_ra[kl] : rp[(k << 5) + o];
    const float4* pk  = (const float4*)s_pose + (kl << 2);
    const float4* wkb = (const float4*)wT + ((size_t)k << 7) + o;
    float4 w0 = wkb[0], w1 = wkb[32], w2 = wkb[64], w3 = wkb[96];
    srr += rra;
#pragma unroll
    for (int a = 0; a < 4; ++a) {
      float4 A = pk[a];
      float v0 = A.x*w0.x + A.y*w0.y + A.z*w0.z + A.w*w0.w;
      float v1 = A.x*w1.x + A.y*w1.y + A.z*w1.z + A.w*w1.w;
      float v2 = A.x*w2.x + A.y*w2.y + A.z*w2.z + A.w*w2.w;
      float v3 = A.x*w3.x + A.y*w3.y + A.z*w3.z + A.w*w3.w;
      float r0 = rra*v0, r1 = rra*v1, r2 = rra*v2, r3 = rra*v3;
      m1[a*4+0] += r0;    m1[a*4+1] += r1;    m1[a*4+2] += r2;    m1[a*4+3] += r3;
      m2[a*4+0] += r0*v0; m2[a*4+1] += r1*v1; m2[a*4+2] += r2*v2; m2[a*4+3] += r3*v3;
    }
  }

  /* combine q-pairs in-wave, then 4 wave-groups via LDS */
  srr += __shfl_xor(srr, 32, 64);
#pragma unroll
  for (int j = 0; j < 16; ++j) {
    m1[j] += __shfl_xor(m1[j], 32, 64);
    m2[j] += __shfl_xor(m2[j], 32, 64);
  }
  {
    const int lane = t & 63, wv = t >> 6;
    if (lane < 32) {
      float* rb = s_red + wv*1056 + lane*33;
      rb[0] = srr;
#pragma unroll
      for (int j = 0; j < 16; ++j) { rb[1+j] = m1[j]; rb[17+j] = m2[j]; }
    }
  }
  __syncthreads();
  float* pb = part + (size_t)(np*4 + k4) * 1056;
  for (int u = t; u < 1056; u += 256) {
    float s = s_red[u] + s_red[1056+u] + s_red[2112+u] + s_red[3168+u];
    pb[u] = s;
  }
}

/* ---- K2: stats (redundant per k4) + zz. grid 1152 k4-major, block 512 ---- */
template<int IT>
__global__ __launch_bounds__(512, 4) void zzstats_kernel(
    const float* __restrict__ inp, const float* __restrict__ wT,
    const float* __restrict__ part,
    const float* __restrict__ beta_v, const float* __restrict__ beta_a,
    float* __restrict__ zzg)
{
  __shared__ float s_pose[72*16];
  __shared__ float s_mean[512];
  __shared__ float s_i2v[512];
  __shared__ float s_cost[OO];
  __shared__ float s_lvs[OO];
  __shared__ float s_lc[OO];

  const int blk = blockIdx.x;
  const int np = blk % 288, k4 = blk / 288;
  const int n = np / P2, p = np % P2;
  const int pr = p / PS, pc = p % PS;
  const int t = threadIdx.x;
  const int k0 = k4 * 72;

  const float* ibase = inp + (size_t)n * (196*32*17);
  for (int e = t; e < 72*4; e += 512) {
    int kl = e >> 2, v4 = e & 3;
    int k = k0 + kl;
    int kk = k >> 5, ci = k & 31;
    const float* src = ibase + (size_t)(((pr*2 + kk/3)*14 + (pc*2 + kk%3))*32 + ci)*17 + v4*4;
    ((float4*)s_pose)[e] = *(const float4*)src;
  }

  /* stats: t = (so,h) */
  {
    const int so = t >> 4, h = t & 15;
    const float* pb = part + (size_t)np * 4224 + so*33;
    float rs = pb[0]        + pb[1056]        + pb[2112]        + pb[3168];
    float a1 = pb[1+h]      + pb[1056+1+h]    + pb[2112+1+h]    + pb[3168+1+h];
    float a2 = pb[17+h]     + pb[1056+17+h]   + pb[2112+17+h]   + pb[3168+17+h];
    float S    = rs + EPSF;
    float mean = a1 / S;
    float var  = fmaxf(a2 / S - mean*mean, 0.f) + EPSF;
    float lvh  = __logf(var);
    float ch   = (beta_v[so] + 0.5f * lvh) * rs;
    float lv   = lvh;
#pragma unroll
    for (int d = 1; d < 16; d <<= 1) {
      ch += __shfl_xor(ch, d, 64);
      lv += __shfl_xor(lv, d, 64);
    }
    s_mean[t] = mean;
    s_i2v[t]  = 0.5f / var;
    if (h == 0) { s_cost[so] = ch; s_lvs[so] = lv; }
  }
  __syncthreads();

  if (t < OO) {
    float cm = 0.f;
#pragma unroll
    for (int oi = 0; oi < OO; ++oi) cm += s_cost[oi];
    cm *= (1.f / OO);
    float ssq = 0.f;
#pragma unroll
    for (int oi = 0; oi < OO; ++oi) { float d = s_cost[oi] - cm; ssq += d*d; }
    float sd = sqrtf(ssq * (1.f / OO));
    const float INVT = (IT==0) ? 5.0e-4f : 9.75e-4f;
    float arg = INVT * (beta_a[t] + (cm - s_cost[t]) / (sd + EPSF));
    float aj  = 1.f / (1.f + __expf(-arg));
    s_lc[t] = __logf(aj + EPSF) - 0.5f * (s_lvs[t] + 16.f * LOG2PI_F);
  }
  __syncthreads();

  /* zz rows r = k_local*32 + oz */
  {
    const int oz = t & 31;
    const float lc = s_lc[oz];
    const float4* mo4 = (const float4*)(s_mean + (oz << 4));
    const float4* io4 = (const float4*)(s_i2v  + (oz << 4));
    float4 M0 = mo4[0], M1 = mo4[1], M2 = mo4[2], M3 = mo4[3];
    float4 I0 = io4[0], I1 = io4[1], I2 = io4[2], I3 = io4[3];
    float* zb = zzg + (size_t)np * KCO + ((size_t)k0 << 5);
    for (int r = t; r < 2304; r += 512) {
      int kl = r >> 5;
      int k  = k0 + kl;
      const float4* pk  = (const float4*)s_pose + (kl << 2);
      const float4* wkb = (const float4*)wT + ((size_t)k << 7) + oz;
      float4 w0 = wkb[0], w1 = wkb[32], w2 = wkb[64], w3 = wkb[96];
      float ssum = 0.f;
      float4 A;
      A = pk[0];
      {
        float x0 = A.x*w0.x + A.y*w0.y + A.z*w0.z + A.w*w0.w;
        float x1 = A.x*w1.x + A.y*w1.y + A.z*w1.z + A.w*w1.w;
        float x2 = A.x*w2.x + A.y*w2.y + A.z*w2.z + A.w*w2.w;
        float x3 = A.x*w3.x + A.y*w3.y + A.z*w3.z + A.w*w3.w;
        float d0 = x0-M0.x, d1 = x1-M0.y, d2 = x2-M0.z, d3 = x3-M0.w;
        ssum += d0*d0*I0.x + d1*d1*I0.y + d2*d2*I0.z + d3*d3*I0.w;
      }
      A = pk[1];
      {
        float x0 = A.x*w0.x + A.y*w0.y + A.z*w0.z + A.w*w0.w;
        float x1 = A.x*w1.x + A.y*w1.y + A.z*w1.z + A.w*w1.w;
        float x2 = A.x*w2.x + A.y*w2.y + A.z*w2.z + A.w*w2.w;
        float x3 = A.x*w3.x + A.y*w3.y + A.z*w3.z + A.w*w3.w;
        float d0 = x0-M1.x, d1 = x1-M1.y, d2 = x2-M1.z, d3 = x3-M1.w;
        ssum += d0*d0*I1.x + d1*d1*I1.y + d2*d2*I1.z + d3*d3*I1.w;
      }
      A = pk[2];
      {
        float x0 = A.x*w0.x + A.y*w0.y + A.z*w0.z + A.w*w0.w;
        float x1 = A.x*w1.x + A.y*w1.y + A.z*w1.z + A.w*w1.w;
        float x2 = A.x*w2.x + A.y*w2.y + A.z*w2.z + A.w*w2.w;
        float x3 = A.x*w3.x + A.y*w3.y + A.z*w3.z + A.w*w3.w;
        float d0 = x0-M2.x, d1 = x1-M2.y, d2 = x2-M2.z, d3 = x3-M2.w;
        ssum += d0*d0*I2.x + d1*d1*I2.y + d2*d2*I2.z + d3*d3*I2.w;
      }
      A = pk[3];
      {
        float x0 = A.x*w0.x + A.y*w0.y + A.z*w0.z + A.w*w0.w;
        float x1 = A.x*w1.x + A.y*w1.y + A.z*w1.z + A.w*w1.w;
        float x2 = A.x*w2.x + A.y*w2.y + A.z*w2.z + A.w*w2.w;
        float x3 = A.x*w3.x + A.y*w3.y + A.z*w3.z + A.w*w3.w;
        float d0 = x0-M3.x, d1 = x1-M3.y, d2 = x2-M3.z, d3 = x3-M3.w;
        ssum += d0*d0*I3.x + d1*d1*I3.y + d2*d2*I3.z + d3*d3*I3.w;
      }
      zb[r] = lc - ssum;
    }
  }
}

/* ---- K3: final stats -> output. grid 288, block 512 ---- */
__global__ __launch_bounds__(512) void statsout_kernel(
    const float* __restrict__ part,
    const float* __restrict__ beta_v, const float* __restrict__ beta_a,
    float* __restrict__ out)
{
  __shared__ float s_cost[OO];
  const int np = blockIdx.x;
  const int t = threadIdx.x;
  const int o = t >> 4, h = t & 15;

  const float* pb = part + (size_t)np * 4224 + o*33;
  float rs = pb[0]    + pb[1056]      + pb[2112]      + pb[3168];
  float a1 = pb[1+h]  + pb[1056+1+h]  + pb[2112+1+h]  + pb[3168+1+h];
  float a2 = pb[17+h] + pb[1056+17+h] + pb[2112+17+h] + pb[3168+17+h];
  float S = rs + EPSF;
  float mean = a1 / S;
  float var  = fmaxf(a2 / S - mean*mean, 0.f) + EPSF;
  float ch   = (beta_v[o] + 0.5f * __logf(var)) * rs;
#pragma unroll
  for (int d = 1; d < 16; d <<= 1) ch += __shfl_xor(ch, d, 64);
  if (h == 0) s_cost[o] = ch;
  __syncthreads();

  float cm = 0.f;
#pragma unroll
  for (int oi = 0; oi < OO; ++oi) cm += s_cost[oi];
  cm *= (1.f / OO);
  float ssq = 0.f;
#pragma unroll
  for (int oi = 0; oi < OO; ++oi) { float d = s_cost[oi] - cm; ssq += d*d; }
  float sd = sqrtf(ssq * (1.f / OO));
  float arg = 1.42625e-3f * (beta_a[o] + (cm - s_cost[o]) / (sd + EPSF));
  float aj  = 1.f / (1.f + __expf(-arg));

  out[((size_t)np*OO + o)*17 + 1 + h] = mean;
  if (h == 0) out[((size_t)np*OO + o)*17] = aj;
}

/* ---- childnorm: 4 parent-slots per (child,ci); writes rr = e*act/den ---- */
__global__ __launch_bounds__(256) void childnorm_kernel(
    const float* __restrict__ inp, const float* __restrict__ zzg,
    float* __restrict__ rrg)
{
  const int tg = blockIdx.x * 256 + threadIdx.x;   /* 43264*4 = 173056 */
  const int g = tg >> 2, slot = tg & 3;
  const int n   = g / (169*32);
  const int rem = g % (169*32);
  const int sc  = rem >> 5, ci = rem & 31;
  const int x = sc / 13, y = sc % 13;

  int base = -1; int cnt = 0;
#pragma unroll
  for (int r = 0; r < 6; ++r) {
    int i = x - 2*r;
    if (i < 0 || i > 2) continue;
#pragma unroll
    for (int c2 = 0; c2 < 6; ++c2) {
      int j = y - 2*c2;
      if (j < 0 || j > 2) continue;
      if (cnt == slot) base = (((n*P2 + r*6+c2)*9 + i*3+j)*CI + ci) << 5;
      ++cnt;
    }
  }

  const float4* z4 = (base >= 0) ? (const float4*)(zzg + base) : (const float4*)zzg;
  float4 zv[8];
#pragma unroll
  for (int q = 0; q < 8; ++q) zv[q] = z4[q];

  float m = -1e30f;
  if (base >= 0) {
#pragma unroll
    for (int q = 0; q < 8; ++q) {
      float4 v = zv[q];
      m = fmaxf(m, fmaxf(fmaxf(v.x, v.y), fmaxf(v.z, v.w)));
    }
  }
  m = fmaxf(m, __shfl_xor(m, 1, 64));
  m = fmaxf(m, __shfl_xor(m, 2, 64));

  float den = 0.f;
  float e[32];
  if (base >= 0) {
#pragma unroll
    for (int q = 0; q < 8; ++q) {
      float4 v = zv[q];
      e[q*4+0] = __expf(v.x - m); e[q*4+1] = __expf(v.y - m);
      e[q*4+2] = __expf(v.z - m); e[q*4+3] = __expf(v.w - m);
      den += e[q*4+0] + e[q*4+1] + e[q*4+2] + e[q*4+3];
    }
  }
  den += __shfl_xor(den, 1, 64);
  den += __shfl_xor(den, 2, 64);

  const float act = inp[(((size_t)n*196 + x*14 + y)*32 + ci)*17 + 16];
  float s = act / (den + EPSF);

  if (base >= 0) {
    float4* r4 = (float4*)(rrg + base);
#pragma unroll
    for (int q = 0; q < 8; ++q) {
      float4 rv;
      rv.x = e[q*4+0]*s; rv.y = e[q*4+1]*s; rv.z = e[q*4+2]*s; rv.w = e[q*4+3]*s;
      r4[q] = rv;
    }
  }
}

extern "C" void kernel_launch(void* const* d_in, const int* in_sizes, int n_in,
                              void* d_out, int out_size, void* d_ws, size_t ws_size,
                              hipStream_t stream)
{
  (void)in_sizes; (void)n_in; (void)out_size; (void)ws_size;
  const float* inp = (const float*)d_in[0];
  const float* w   = (const float*)d_in[1];
  const float* bv  = (const float*)d_in[2];
  const float* ba  = (const float*)d_in[3];
  float* out = (float*)d_out;
  float* ws  = (float*)d_ws;
  float* zz   = ws + ZZ_OFF;
  float* rr   = ws + RR_OFF;
  float* wT   = ws + WT_OFF;
  float* part = ws + PART_OFF;

  wtrans_kernel<<<576, 256, 0, stream>>>(w, wT);

  moments_kernel<true ><<<1152, 256, 0, stream>>>(inp, wT, rr, part);
  zzstats_kernel<0><<<1152, 512, 0, stream>>>(inp, wT, part, bv, ba, zz);
  childnorm_kernel<<<676, 256, 0, stream>>>(inp, zz, rr);

  moments_kernel<false><<<1152, 256, 0, stream>>>(inp, wT, rr, part);
  zzstats_kernel<1><<<1152, 512, 0, stream>>>(inp, wT, part, bv, ba, zz);
  childnorm_kernel<<<676, 256, 0, stream>>>(inp, zz, rr);

  moments_kernel<false><<<1152, 256, 0, stream>>>(inp, wT, rr, part);
  statsout_kernel<<<288, 512, 0, stream>>>(part, bv, ba, out);
}